// Round 14
// baseline (110.255 us; speedup 1.0000x reference)
//
#include <hip/hip_runtime.h>
#include <hip/hip_bf16.h>
#include <stdint.h>

#define S_LEN 2048
#define DIM   1024
#define NH    16
#define HD    64
#define BATCH 2

typedef __attribute__((ext_vector_type(4))) float f32x4;
typedef __attribute__((ext_vector_type(16))) float f32x16;
typedef __attribute__((ext_vector_type(8))) short bf16x8;
typedef __attribute__((ext_vector_type(4))) int i32x4;
typedef __hip_bfloat16 bf16;

__device__ inline void gload_lds16(const void* g, void* l) {
  __builtin_amdgcn_global_load_lds(
      (const __attribute__((address_space(1))) void*)g,
      (__attribute__((address_space(3))) void*)l, 16, 0, 0);
}

__device__ inline bf16x8 as_bf16x8(i32x4 x) {
  union { i32x4 i; bf16x8 v; } u; u.i = x; return u.v;
}
__device__ inline int cvt_pk_bf16(float lo, float hi) {
  int r;
  asm("v_cvt_pk_bf16_f32 %0, %1, %2" : "=v"(r) : "v"(lo), "v"(hi));
  return r;
}
__device__ inline float b2f(short s) {
  union { unsigned int u; float f; } w;
  w.u = ((unsigned int)(unsigned short)s) << 16;
  return w.f;
}

// ---------------- fused fp32 -> bf16 conversion (all 5 inputs) ----------------
__global__ __launch_bounds__(256) void cvt_all(
    const float* __restrict__ q, const float* __restrict__ c,
    const float* __restrict__ wq, const float* __restrict__ wkv,
    const float* __restrict__ wo,
    bf16* __restrict__ oq, bf16* __restrict__ oc, bf16* __restrict__ owq,
    bf16* __restrict__ owkv, bf16* __restrict__ owo) {
  const int N0 = 1048576, N1 = 1048576, N2 = 262144, N3 = 524288, N4 = 262144;
  const int total = N0 + N1 + N2 + N3 + N4;
  for (int i = blockIdx.x * 256 + threadIdx.x; i < total; i += gridDim.x * 256) {
    const float* src; bf16* dst; int off = i;
    if (i < N0)                { src = q;   dst = oq; }
    else if (i < N0 + N1)      { src = c;   dst = oc;   off -= N0; }
    else if (i < N0 + N1 + N2) { src = wq;  dst = owq;  off -= N0 + N1; }
    else if (i < N0 + N1 + N2 + N3) { src = wkv; dst = owkv; off -= N0 + N1 + N2; }
    else                       { src = wo;  dst = owo;  off -= N0 + N1 + N2 + N3; }
    float4 v = ((const float4*)src)[off];
    bf16 b0 = __float2bfloat16(v.x), b1 = __float2bfloat16(v.y);
    bf16 b2 = __float2bfloat16(v.z), b3 = __float2bfloat16(v.w);
    ushort4 o;
    o.x = *(unsigned short*)&b0; o.y = *(unsigned short*)&b1;
    o.z = *(unsigned short*)&b2; o.w = *(unsigned short*)&b3;
    ((ushort4*)dst)[off] = o;
  }
}

// ---------------- pipelined 128x128 GEMM body (counted-vmcnt, triple-buffer) ----------------
__device__ inline void gemm128_pipe(const bf16* __restrict__ A, const bf16* __restrict__ B,
                                    bf16* __restrict__ C, int N, int K, float alpha,
                                    int bm, int bn,
                                    bf16 (*Als)[128 * 32], bf16 (*Bls)[128 * 32]) {
  const int tid = threadIdx.x;
  const int lane = tid & 63, wid = tid >> 6;
  const int wr = wid >> 1, wc = wid & 1;
  const int fr = lane & 15, fq = lane >> 4;

  f32x4 acc[4][4] = {};
  const int nt = K >> 5;

  auto stage = [&](int buf, int kt) {
    const int k0 = kt << 5;
#pragma unroll
    for (int j = 0; j < 2; ++j) {
      int ob = wid * 2048 + j * 1024;
      int o = ob + lane * 16;
      int r = o >> 6;
      int kk = (o & 63) >> 1;
      gload_lds16(A + (size_t)(bm + r) * K + k0 + kk, (char*)Als[buf] + ob);
      gload_lds16(B + (size_t)(bn + r) * K + k0 + kk, (char*)Bls[buf] + ob);
    }
  };

  stage(0, 0);
  stage(1, 1);  // K >= 64 always here

  for (int i = 0; i < nt; ++i) {
    if (i + 1 < nt) asm volatile("s_waitcnt vmcnt(4)" ::: "memory");
    else            asm volatile("s_waitcnt vmcnt(0)" ::: "memory");
    __builtin_amdgcn_s_barrier();
    __builtin_amdgcn_sched_barrier(0);

    const int cb = i % 3;
    bf16x8 af[4], bfr[4];
#pragma unroll
    for (int m = 0; m < 4; ++m)
      af[m] = *(const bf16x8*)(Als[cb] + (wr * 64 + m * 16 + fr) * 32 + fq * 8);
#pragma unroll
    for (int n = 0; n < 4; ++n)
      bfr[n] = *(const bf16x8*)(Bls[cb] + (wc * 64 + n * 16 + fr) * 32 + fq * 8);
    __builtin_amdgcn_s_setprio(1);
#pragma unroll
    for (int m = 0; m < 4; ++m)
#pragma unroll
      for (int n = 0; n < 4; ++n)
        acc[m][n] = __builtin_amdgcn_mfma_f32_16x16x32_bf16(af[m], bfr[n], acc[m][n], 0, 0, 0);
    __builtin_amdgcn_s_setprio(0);

    if (i + 2 < nt) stage((i + 2) % 3, i + 2);  // 2-deep prefetch
  }

#pragma unroll
  for (int m = 0; m < 4; ++m)
#pragma unroll
    for (int n = 0; n < 4; ++n)
#pragma unroll
      for (int i = 0; i < 4; ++i) {
        int row = bm + wr * 64 + m * 16 + fq * 4 + i;
        int col = bn + wc * 64 + n * 16 + fr;
        C[(size_t)row * N + col] = __float2bfloat16(acc[m][n][i] * alpha);
      }
}

// Q-proj (256 blocks) + KV-proj (512 blocks) grouped; bijective XCD swizzle (768 = 8*96).
__global__ __launch_bounds__(256) void gemm_proj(
    const bf16* __restrict__ Aq, const bf16* __restrict__ Bq, bf16* __restrict__ Cq,
    const bf16* __restrict__ Akv, const bf16* __restrict__ Bkv, bf16* __restrict__ Ckv,
    float qalpha) {
  __shared__ __align__(16) bf16 Als[3][128 * 32];
  __shared__ __align__(16) bf16 Bls[3][128 * 32];
  const int bid0 = blockIdx.x;
  const int bid = (bid0 & 7) * 96 + (bid0 >> 3);  // XCD-contiguous chunks
  const bf16 *A, *B; bf16 *C; int N; float alpha; int bx, by;
  if (bid < 256) { A = Aq;  B = Bq;  C = Cq;  N = 1024; alpha = qalpha; bx = bid & 7;  by = bid >> 3; }
  else { int t = bid - 256; A = Akv; B = Bkv; C = Ckv; N = 2048; alpha = 1.0f; bx = t & 15; by = t >> 4; }
  gemm128_pipe(A, B, C, N, 1024, alpha, by * 128, bx * 128, Als, Bls);
}

// ---------------- out-proj GEMM: BM=128, BN=64, pipelined (fp32 out), 1D grid of 512 ----------------
__global__ __launch_bounds__(256) void gemm_bt_n64(
    const bf16* __restrict__ A, const bf16* __restrict__ B,
    float* __restrict__ C, int M, int N, int K) {
  __shared__ __align__(16) bf16 Als[3][128 * 32];
  __shared__ __align__(16) bf16 Bls[3][64 * 32];
  const int tid = threadIdx.x;
  const int lane = tid & 63, wid = tid >> 6;
  const int bid0 = blockIdx.x;                    // [0,512)
  const int bid = (bid0 & 7) * 64 + (bid0 >> 3);  // 512 = 8*64 bijective
  const int bx = bid & 15, by = bid >> 4;         // 16 x 32 tiles
  const int bm = by * 128, bn = bx * 64;
  const int fr = lane & 15, fq = lane >> 4;

  f32x4 acc[2][4] = {};
  const int nt = K >> 5;

  auto stage = [&](int buf, int kt) {
    const int k0 = kt << 5;
#pragma unroll
    for (int j = 0; j < 2; ++j) {
      int ob = wid * 2048 + j * 1024;
      int o = ob + lane * 16;
      int r = o >> 6;
      int kk = (o & 63) >> 1;
      gload_lds16(A + (size_t)(bm + r) * K + k0 + kk, (char*)Als[buf] + ob);
    }
    {
      int ob = wid * 1024;
      int o = ob + lane * 16;
      int r = o >> 6;
      int kk = (o & 63) >> 1;
      gload_lds16(B + (size_t)(bn + r) * K + k0 + kk, (char*)Bls[buf] + ob);
    }
  };

  stage(0, 0);
  stage(1, 1);

  for (int i = 0; i < nt; ++i) {
    if (i + 1 < nt) asm volatile("s_waitcnt vmcnt(3)" ::: "memory");
    else            asm volatile("s_waitcnt vmcnt(0)" ::: "memory");
    __builtin_amdgcn_s_barrier();
    __builtin_amdgcn_sched_barrier(0);

    const int cb = i % 3;
    bf16x8 af[2], bfr[4];
#pragma unroll
    for (int m = 0; m < 2; ++m)
      af[m] = *(const bf16x8*)(Als[cb] + (wid * 32 + m * 16 + fr) * 32 + fq * 8);
#pragma unroll
    for (int n = 0; n < 4; ++n)
      bfr[n] = *(const bf16x8*)(Bls[cb] + (n * 16 + fr) * 32 + fq * 8);
    __builtin_amdgcn_s_setprio(1);
#pragma unroll
    for (int m = 0; m < 2; ++m)
#pragma unroll
      for (int n = 0; n < 4; ++n)
        acc[m][n] = __builtin_amdgcn_mfma_f32_16x16x32_bf16(af[m], bfr[n], acc[m][n], 0, 0, 0);
    __builtin_amdgcn_s_setprio(0);

    if (i + 2 < nt) stage((i + 2) % 3, i + 2);
  }

#pragma unroll
  for (int m = 0; m < 2; ++m)
#pragma unroll
    for (int n = 0; n < 4; ++n)
#pragma unroll
      for (int i = 0; i < 4; ++i) {
        int row = bm + wid * 32 + m * 16 + fq * 4 + i;
        int col = bn + n * 16 + fr;
        C[(size_t)row * N + col] = acc[m][n][i];
      }
}

// ---------------- V transpose: Vt[b][h][a][s] = KV[b*S+s][DIM + h*HD + a] ----------------
__global__ __launch_bounds__(256) void transpose_v(
    const bf16* __restrict__ KV, bf16* __restrict__ Vt) {
  __shared__ __align__(16) bf16 tile[64][72];
  const int t = threadIdx.x;
  const int s0 = blockIdx.x * 64, h = blockIdx.y, b = blockIdx.z;
#pragma unroll
  for (int j = 0; j < 2; ++j) {
    int s = j * 32 + (t >> 3);
    int a = (t & 7) * 8;
    bf16x8 v = *(const bf16x8*)(KV + (size_t)(b * S_LEN + s0 + s) * (2 * DIM) + DIM + h * HD + a);
    *(bf16x8*)&tile[s][a] = v;
  }
  __syncthreads();
#pragma unroll
  for (int j = 0; j < 2; ++j) {
    int a = j * 32 + (t >> 3);
    int sc = (t & 7) * 8;
    bf16x8 v;
#pragma unroll
    for (int e = 0; e < 8; ++e)
      ((short*)&v)[e] = *(const short*)&tile[sc + e][a];
    *(bf16x8*)(Vt + (size_t)((b * NH + h) * HD + a) * S_LEN + s0 + sc) = v;
  }
}

// ---------------- Flash attention, key-split x2, counted-vmcnt pipeline ----------------
// 1024 blocks heavy-first: block = (b,h,qx,chunk); chunk = (qx+1) 64-key tiles.
// 3 buffers, 2-deep prefetch, vmcnt(4). Row-sums accumulated on the MFMA pipe via ones-B.
__global__ __launch_bounds__(256, 4) void attn_fwd(
    const bf16* __restrict__ Q,     // [B*S][DIM] (pre-scaled by log2e/sqrt(D))
    const bf16* __restrict__ KV,    // [B*S][2*DIM] (K = first DIM cols)
    const bf16* __restrict__ Vt,    // [B*NH][HD][S]
    bf16* __restrict__ Opart,       // [1024][128][64] unnormalized partial O
    float* __restrict__ Rpart) {    // [1024][128] partial row sums
  __shared__ __align__(16) bf16 Kls[3][64 * 64];  // [key][a], 128B rows, xor-swizzled
  __shared__ __align__(16) bf16 Vls[3][64 * 64];  // [a][key], 128B rows, xor-swizzled
  const int tid = threadIdx.x, lane = tid & 63, wid = tid >> 6;
  const int l31 = lane & 31, hi = lane >> 5;
  const int bid = blockIdx.x;
  const int qx = 15 - (bid >> 6);   // heavy q-blocks dispatch first
  const int rem = bid & 63;
  const int c = rem >> 5;           // key chunk 0/1
  const int hb = rem & 31;
  const int h = hb >> 1, b = hb & 1;
  const int rw0 = qx * 128 + wid * 32;
  const int qrow = rw0 + l31;
  const float NEGINF = -__builtin_inff();

  const int cnt = qx + 1;           // tiles in this chunk
  const int kt0 = c * cnt;          // first tile
  const int p = ((b * NH + h) * 32) + qx * 2 + c;  // partial index

  bf16x8 qf[4];
#pragma unroll
  for (int ka = 0; ka < 4; ++ka)
    qf[ka] = *(const bf16x8*)(Q + (size_t)(b * S_LEN + qrow) * DIM + h * HD + ka * 16 + hi * 8);

  // all-ones bf16 B-operand for row-sum MFMA
  i32x4 onesw;
  onesw[0] = 0x3F803F80; onesw[1] = 0x3F803F80; onesw[2] = 0x3F803F80; onesw[3] = 0x3F803F80;
  const bf16x8 onesf = as_bf16x8(onesw);

  f32x16 oacc[2] = {};
  f32x16 rsacc = {};   // rsacc[r] = rowsum(q = crow(r,hi)), same in all lanes of a half

  // hoisted staging addresses: per-call cost is base + kt*const
  const bf16* kA[2]; const bf16* vA[2]; int obA[2];
#pragma unroll
  for (int j = 0; j < 2; ++j) {
    int ob = (wid * 2 + j) * 1024;
    int o = ob + lane * 16;
    int r = o >> 7;
    int sb = (o & 127) ^ ((r & 7) << 4);
    kA[j] = KV + (size_t)(b * S_LEN + r) * (2 * DIM) + h * HD + (sb >> 1);
    vA[j] = Vt + (size_t)((b * NH + h) * HD + r) * S_LEN + (sb >> 1);
    obA[j] = ob;
  }
  const size_t kStep = (size_t)64 * 2 * DIM;  // K rows advance per tile
  auto stage = [&](int buf, int kt) {
#pragma unroll
    for (int j = 0; j < 2; ++j) {
      gload_lds16(kA[j] + (size_t)kt * kStep, (char*)Kls[buf] + obA[j]);
      gload_lds16(vA[j] + (size_t)kt * 64, (char*)Vls[buf] + obA[j]);
    }
  };

  stage(0, kt0);
  if (cnt > 1) stage(1, kt0 + 1);

  for (int i = 0; i < cnt; ++i) {
    const int kt = kt0 + i;
    if (i + 1 < cnt) asm volatile("s_waitcnt vmcnt(4)" ::: "memory");
    else             asm volatile("s_waitcnt vmcnt(0)" ::: "memory");
    __builtin_amdgcn_s_barrier();
    __builtin_amdgcn_sched_barrier(0);

    const int cb = i % 3;
    if (64 * kt <= rw0 + 31) {
      const bf16* Kb = Kls[cb];
      const bf16* Vb = Vls[cb];
      const bool maskt = (64 * kt + 63 > rw0);

#pragma unroll
      for (int kb = 0; kb < 2; ++kb) {
        f32x16 cc = {};
        __builtin_amdgcn_s_setprio(1);
#pragma unroll
        for (int ka = 0; ka < 4; ++ka) {
          int row = kb * 32 + l31;
          bf16x8 kf = *(const bf16x8*)((const char*)Kb + row * 128 +
                                       ((ka * 32 + hi * 16) ^ ((row & 7) << 4)));
          cc = __builtin_amdgcn_mfma_f32_32x32x16_bf16(kf, qf[ka], cc, 0, 0, 0);
        }
        __builtin_amdgcn_s_setprio(0);

        float pe[16];
        if (maskt) {
#pragma unroll
          for (int r = 0; r < 16; ++r) {
            int key = kt * 64 + kb * 32 + (r & 3) + 8 * (r >> 2) + 4 * hi;
            float s = (key <= qrow) ? cc[r] : NEGINF;
            pe[r] = __builtin_amdgcn_exp2f(s);
          }
        } else {
#pragma unroll
          for (int r = 0; r < 16; ++r)
            pe[r] = __builtin_amdgcn_exp2f(cc[r]);
        }

        int u0 = cvt_pk_bf16(pe[0], pe[1]),  u1 = cvt_pk_bf16(pe[2], pe[3]);
        int u2 = cvt_pk_bf16(pe[4], pe[5]),  u3 = cvt_pk_bf16(pe[6], pe[7]);
        int u4 = cvt_pk_bf16(pe[8], pe[9]),  u5 = cvt_pk_bf16(pe[10], pe[11]);
        int u6 = cvt_pk_bf16(pe[12], pe[13]), u7 = cvt_pk_bf16(pe[14], pe[15]);
        asm("v_permlane32_swap_b32 %0, %1" : "+v"(u0), "+v"(u2));
        asm("v_permlane32_swap_b32 %0, %1" : "+v"(u1), "+v"(u3));
        asm("v_permlane32_swap_b32 %0, %1" : "+v"(u4), "+v"(u6));
        asm("v_permlane32_swap_b32 %0, %1" : "+v"(u5), "+v"(u7));
        i32x4 w0, w1;
        w0[0] = u0; w0[1] = u1; w0[2] = u2; w0[3] = u3;
        w1[0] = u4; w1[1] = u5; w1[2] = u6; w1[3] = u7;
        bf16x8 pa0 = as_bf16x8(w0), pa1 = as_bf16x8(w1);

        __builtin_amdgcn_s_setprio(1);
        // row-sums on the matrix pipe: D[r][*] += sum_k pa[r][k] * 1
        rsacc = __builtin_amdgcn_mfma_f32_32x32x16_bf16(pa0, onesf, rsacc, 0, 0, 0);
        rsacc = __builtin_amdgcn_mfma_f32_32x32x16_bf16(pa1, onesf, rsacc, 0, 0, 0);
#pragma unroll
        for (int pl = 0; pl < 2; ++pl) {
          bf16x8 pa = pl ? pa1 : pa0;
#pragma unroll
          for (int nb = 0; nb < 2; ++nb) {
            int a = nb * 32 + l31;
            bf16x8 vf = *(const bf16x8*)((const char*)Vb + a * 128 +
                                         ((kb * 64 + pl * 32 + hi * 16) ^ ((a & 7) << 4)));
            oacc[nb] = __builtin_amdgcn_mfma_f32_32x32x16_bf16(pa, vf, oacc[nb], 0, 0, 0);
          }
        }
        __builtin_amdgcn_s_setprio(0);
      }
    }

    if (i + 2 < cnt) stage((i + 2) % 3, kt0 + i + 2);
  }

  // rsacc[r] identical across all 32 columns; lane col 0 of each half writes.
  if (l31 == 0) {
#pragma unroll
    for (int r = 0; r < 16; ++r) {
      int qloc = (r & 3) + 8 * (r >> 2) + 4 * hi;
      Rpart[p * 128 + wid * 32 + qloc] = rsacc[r];
    }
  }
#pragma unroll
  for (int nb = 0; nb < 2; ++nb)
#pragma unroll
    for (int r = 0; r < 16; ++r) {
      int qloc = (r & 3) + 8 * (r >> 2) + 4 * hi;
      Opart[(size_t)p * 8192 + (wid * 32 + qloc) * 64 + nb * 32 + l31] =
          __float2bfloat16(oacc[nb][r]);
    }
}

// ---------------- combine: O = (O0 + O1) / (r0 + r1) ----------------
__global__ __launch_bounds__(256) void attn_combine(
    const bf16* __restrict__ Opart, const float* __restrict__ Rpart,
    bf16* __restrict__ O) {
  const int g = blockIdx.x;          // (b*NH+h)*16 + qx
  const int qx = g & 15, bh = g >> 4;
  const int h = bh & 15, b = bh >> 4;
  const int t = threadIdx.x;
  const int row = t >> 1, col0 = (t & 1) * 32;
  const int p0 = bh * 32 + qx * 2;
  const size_t o0 = (size_t)p0 * 8192 + row * 64 + col0;
  const float rinv = 1.0f / (Rpart[p0 * 128 + row] + Rpart[p0 * 128 + 128 + row]);
  const int s = qx * 128 + row;
  bf16* dst = O + (size_t)(b * S_LEN + s) * DIM + h * HD + col0;
#pragma unroll
  for (int j = 0; j < 4; ++j) {
    bf16x8 a = *(const bf16x8*)(Opart + o0 + j * 8);
    bf16x8 cc = *(const bf16x8*)(Opart + o0 + 8192 + j * 8);
    bf16x8 w;
#pragma unroll
    for (int e = 0; e < 8; ++e) {
      bf16 r = __float2bfloat16((b2f(a[e]) + b2f(cc[e])) * rinv);
      ((short*)&w)[e] = *(short*)&r;
    }
    *(bf16x8*)(dst + j * 8) = w;
  }
}

// ---------------- launch ----------------
extern "C" void kernel_launch(void* const* d_in, const int* in_sizes, int n_in,
                              void* d_out, int out_size, void* d_ws, size_t ws_size,
                              hipStream_t stream) {
  (void)in_sizes; (void)n_in; (void)out_size; (void)ws_size;
  const float* query   = (const float*)d_in[0];
  const float* context = (const float*)d_in[1];
  const float* Wq      = (const float*)d_in[2];
  const float* Wkv     = (const float*)d_in[3];
  const float* Wout    = (const float*)d_in[4];
  float* out = (float*)d_out;

  bf16* ws = (bf16*)d_ws;
  const size_t nBSD = (size_t)BATCH * S_LEN * DIM;  // 4194304
  bf16* qbf    = ws;
  bf16* cbf    = qbf + nBSD;
  bf16* wqbf   = cbf + nBSD;
  bf16* wkvbf  = wqbf + (size_t)DIM * DIM;
  bf16* woutbf = wkvbf + (size_t)2 * DIM * DIM;
  bf16* Qp     = woutbf + (size_t)DIM * DIM;
  bf16* KVp    = Qp + nBSD;
  bf16* Vtp    = KVp + 2 * nBSD;
  bf16* Op     = Vtp + nBSD;
  // after gemm_proj, qbf/cbf/wqbf are dead -> reuse for attention partials
  bf16*  Opart = qbf;            // 1024*128*64 bf16 = 16.8 MB
  float* Rpart = (float*)wqbf;   // 1024*128 fp32 = 512 KB

  // fused conversions
  cvt_all<<<2048, 256, 0, stream>>>(query, context, Wq, Wkv, Wout,
                                    qbf, cbf, wqbf, wkvbf, woutbf);

  // Q-proj (scaled by log2e/sqrt(D)) + KV-proj grouped: 768 blocks, pipelined
  gemm_proj<<<768, 256, 0, stream>>>(qbf, wqbf, Qp, cbf, wkvbf, KVp, 0.0450842200277801f);

  // Vt (LDS-transposed, coalesced)
  transpose_v<<<dim3(S_LEN / 64, NH, BATCH), 256, 0, stream>>>(KVp, Vtp);
  // attention: 1024 key-split blocks, heavy-first
  attn_fwd<<<1024, 256, 0, stream>>>(Qp, KVp, Vtp, Opart, Rpart);
  // combine partials -> Op
  attn_combine<<<512, 256, 0, stream>>>(Opart, Rpart, Op);
  // out = O * Wout^T  (BN=64 -> 512 blocks, pipelined, 1D grid)
  const int M = BATCH * S_LEN;
  gemm_bt_n64<<<512, 256, 0, stream>>>(Op, woutbf, out, M, DIM, DIM);
}

// Round 15
// 103.450 us; speedup vs baseline: 1.0658x; 1.0658x over previous
//
#include <hip/hip_runtime.h>
#include <hip/hip_bf16.h>
#include <stdint.h>

#define S_LEN 2048
#define DIM   1024
#define NH    16
#define HD    64
#define BATCH 2

typedef __attribute__((ext_vector_type(4))) float f32x4;
typedef __attribute__((ext_vector_type(16))) float f32x16;
typedef __attribute__((ext_vector_type(8))) short bf16x8;
typedef __attribute__((ext_vector_type(4))) int i32x4;
typedef __hip_bfloat16 bf16;

__device__ inline void gload_lds16(const void* g, void* l) {
  __builtin_amdgcn_global_load_lds(
      (const __attribute__((address_space(1))) void*)g,
      (__attribute__((address_space(3))) void*)l, 16, 0, 0);
}

__device__ inline bf16x8 as_bf16x8(i32x4 x) {
  union { i32x4 i; bf16x8 v; } u; u.i = x; return u.v;
}
__device__ inline int cvt_pk_bf16(float lo, float hi) {
  int r;
  asm("v_cvt_pk_bf16_f32 %0, %1, %2" : "=v"(r) : "v"(lo), "v"(hi));
  return r;
}
__device__ inline float b2f(short s) {
  union { unsigned int u; float f; } w;
  w.u = ((unsigned int)(unsigned short)s) << 16;
  return w.f;
}

// ---------------- fused fp32 -> bf16 conversion (all 5 inputs) ----------------
__global__ __launch_bounds__(256) void cvt_all(
    const float* __restrict__ q, const float* __restrict__ c,
    const float* __restrict__ wq, const float* __restrict__ wkv,
    const float* __restrict__ wo,
    bf16* __restrict__ oq, bf16* __restrict__ oc, bf16* __restrict__ owq,
    bf16* __restrict__ owkv, bf16* __restrict__ owo) {
  const int N0 = 1048576, N1 = 1048576, N2 = 262144, N3 = 524288, N4 = 262144;
  const int total = N0 + N1 + N2 + N3 + N4;
  for (int i = blockIdx.x * 256 + threadIdx.x; i < total; i += gridDim.x * 256) {
    const float* src; bf16* dst; int off = i;
    if (i < N0)                { src = q;   dst = oq; }
    else if (i < N0 + N1)      { src = c;   dst = oc;   off -= N0; }
    else if (i < N0 + N1 + N2) { src = wq;  dst = owq;  off -= N0 + N1; }
    else if (i < N0 + N1 + N2 + N3) { src = wkv; dst = owkv; off -= N0 + N1 + N2; }
    else                       { src = wo;  dst = owo;  off -= N0 + N1 + N2 + N3; }
    float4 v = ((const float4*)src)[off];
    bf16 b0 = __float2bfloat16(v.x), b1 = __float2bfloat16(v.y);
    bf16 b2 = __float2bfloat16(v.z), b3 = __float2bfloat16(v.w);
    ushort4 o;
    o.x = *(unsigned short*)&b0; o.y = *(unsigned short*)&b1;
    o.z = *(unsigned short*)&b2; o.w = *(unsigned short*)&b3;
    ((ushort4*)dst)[off] = o;
  }
}

// ---------------- pipelined 128x128 GEMM core: fills acc, no C write ----------------
__device__ inline void gemm128_core(const bf16* __restrict__ A, const bf16* __restrict__ B,
                                    int K, int bm, int bn,
                                    bf16 (*Als)[4096], bf16 (*Bls)[4096],
                                    f32x4 acc[4][4]) {
  const int tid = threadIdx.x;
  const int lane = tid & 63, wid = tid >> 6;
  const int wr = wid >> 1, wc = wid & 1;
  const int fr = lane & 15, fq = lane >> 4;
  const int nt = K >> 5;

  auto stage = [&](int buf, int kt) {
    const int k0 = kt << 5;
#pragma unroll
    for (int j = 0; j < 2; ++j) {
      int ob = wid * 2048 + j * 1024;
      int o = ob + lane * 16;
      int r = o >> 6;
      int kk = (o & 63) >> 1;
      gload_lds16(A + (size_t)(bm + r) * K + k0 + kk, (char*)Als[buf] + ob);
      gload_lds16(B + (size_t)(bn + r) * K + k0 + kk, (char*)Bls[buf] + ob);
    }
  };

  stage(0, 0);
  stage(1, 1);  // K >= 64 always here

  for (int i = 0; i < nt; ++i) {
    if (i + 1 < nt) asm volatile("s_waitcnt vmcnt(4)" ::: "memory");
    else            asm volatile("s_waitcnt vmcnt(0)" ::: "memory");
    __builtin_amdgcn_s_barrier();
    __builtin_amdgcn_sched_barrier(0);

    const int cb = i % 3;
    bf16x8 af[4], bfr[4];
#pragma unroll
    for (int m = 0; m < 4; ++m)
      af[m] = *(const bf16x8*)(Als[cb] + (wr * 64 + m * 16 + fr) * 32 + fq * 8);
#pragma unroll
    for (int n = 0; n < 4; ++n)
      bfr[n] = *(const bf16x8*)(Bls[cb] + (wc * 64 + n * 16 + fr) * 32 + fq * 8);
    __builtin_amdgcn_s_setprio(1);
#pragma unroll
    for (int m = 0; m < 4; ++m)
#pragma unroll
      for (int n = 0; n < 4; ++n)
        acc[m][n] = __builtin_amdgcn_mfma_f32_16x16x32_bf16(af[m], bfr[n], acc[m][n], 0, 0, 0);
    __builtin_amdgcn_s_setprio(0);

    if (i + 2 < nt) stage((i + 2) % 3, i + 2);  // 2-deep prefetch
  }
}

// Q-proj (256 blocks) + KV-proj (512 blocks) grouped; bijective XCD swizzle (768 = 8*96).
// V-half blocks (bx>=8 of the KV gemm) transpose their 128x128 tile through LDS and
// write Vt[(b*1024+ag)][s] directly with coalesced 16B stores (replaces transpose_v).
__global__ __launch_bounds__(256) void gemm_proj(
    const bf16* __restrict__ Aq, const bf16* __restrict__ Bq, bf16* __restrict__ Cq,
    const bf16* __restrict__ Akv, const bf16* __restrict__ Bkv, bf16* __restrict__ Ckv,
    bf16* __restrict__ Vt, float qalpha) {
  __shared__ __align__(16) bf16 shmem[6 * 4096];  // 48 KB: 3x(A,B) staging; reused for transpose
  bf16 (*Als)[4096] = (bf16(*)[4096])shmem;
  bf16 (*Bls)[4096] = (bf16(*)[4096])(shmem + 3 * 4096);

  const int bid0 = blockIdx.x;
  const int bid = (bid0 & 7) * 96 + (bid0 >> 3);  // XCD-contiguous chunks
  const bf16 *A, *B; bf16 *C; int N; float alpha; int bx, by;
  if (bid < 256) { A = Aq;  B = Bq;  C = Cq;  N = 1024; alpha = qalpha; bx = bid & 7;  by = bid >> 3; }
  else { int t = bid - 256; A = Akv; B = Bkv; C = Ckv; N = 2048; alpha = 1.0f; bx = t & 15; by = t >> 4; }
  const bool vtmode = (bid >= 256) && (bx >= 8);
  const int bm = by * 128, bn = bx * 128;

  f32x4 acc[4][4] = {};
  gemm128_core(A, B, 1024, bm, bn, Als, Bls, acc);

  const int tid = threadIdx.x;
  const int lane = tid & 63, wid = tid >> 6;
  const int wr = wid >> 1, wc = wid & 1;
  const int fr = lane & 15, fq = lane >> 4;

  if (!vtmode) {
#pragma unroll
    for (int m = 0; m < 4; ++m)
#pragma unroll
      for (int n = 0; n < 4; ++n)
#pragma unroll
        for (int i = 0; i < 4; ++i) {
          int row = bm + wr * 64 + m * 16 + fq * 4 + i;
          int col = bn + wc * 64 + n * 16 + fr;
          C[(size_t)row * N + col] = __float2bfloat16(acc[m][n][i] * alpha);
        }
  } else {
    // LDS transpose: T[tcol][trow], padded stride 136 (17408 els = 34.8 KB <= 48 KB)
    const int TP = 136;
    __syncthreads();  // all waves done with staging-buffer LDS reads
#pragma unroll
    for (int m = 0; m < 4; ++m)
#pragma unroll
      for (int n = 0; n < 4; ++n) {
        int tcol = wc * 64 + n * 16 + fr;
#pragma unroll
        for (int i = 0; i < 4; ++i) {
          int trow = wr * 64 + m * 16 + fq * 4 + i;
          shmem[tcol * TP + trow] = __float2bfloat16(acc[m][n][i]);
        }
      }
    __syncthreads();
    const int bb = bm >> 11, s0 = bm & 2047;
    const int vtrow0 = bb * 1024 + (bn - 1024);  // linear (b*1024 + ag)
#pragma unroll
    for (int j = 0; j < 8; ++j) {
      int ar = (tid >> 4) + j * 16;      // Vt row within tile (a-dim)
      int sc = (tid & 15) * 8;           // s-offset (8 elems, 16B)
      bf16x8 v = *(const bf16x8*)&shmem[ar * TP + sc];
      *(bf16x8*)(Vt + (size_t)(vtrow0 + ar) * S_LEN + s0 + sc) = v;
    }
  }
}

// ---------------- out-proj GEMM: BM=128, BN=64, pipelined (fp32 out), 1D grid of 512 ----------------
__global__ __launch_bounds__(256) void gemm_bt_n64(
    const bf16* __restrict__ A, const bf16* __restrict__ B,
    float* __restrict__ C, int M, int N, int K) {
  __shared__ __align__(16) bf16 Als[3][128 * 32];
  __shared__ __align__(16) bf16 Bls[3][64 * 32];
  const int tid = threadIdx.x;
  const int lane = tid & 63, wid = tid >> 6;
  const int bid0 = blockIdx.x;                    // [0,512)
  const int bid = (bid0 & 7) * 64 + (bid0 >> 3);  // 512 = 8*64 bijective
  const int bx = bid & 15, by = bid >> 4;         // 16 x 32 tiles
  const int bm = by * 128, bn = bx * 64;
  const int fr = lane & 15, fq = lane >> 4;

  f32x4 acc[2][4] = {};
  const int nt = K >> 5;

  auto stage = [&](int buf, int kt) {
    const int k0 = kt << 5;
#pragma unroll
    for (int j = 0; j < 2; ++j) {
      int ob = wid * 2048 + j * 1024;
      int o = ob + lane * 16;
      int r = o >> 6;
      int kk = (o & 63) >> 1;
      gload_lds16(A + (size_t)(bm + r) * K + k0 + kk, (char*)Als[buf] + ob);
    }
    {
      int ob = wid * 1024;
      int o = ob + lane * 16;
      int r = o >> 6;
      int kk = (o & 63) >> 1;
      gload_lds16(B + (size_t)(bn + r) * K + k0 + kk, (char*)Bls[buf] + ob);
    }
  };

  stage(0, 0);
  stage(1, 1);

  for (int i = 0; i < nt; ++i) {
    if (i + 1 < nt) asm volatile("s_waitcnt vmcnt(3)" ::: "memory");
    else            asm volatile("s_waitcnt vmcnt(0)" ::: "memory");
    __builtin_amdgcn_s_barrier();
    __builtin_amdgcn_sched_barrier(0);

    const int cb = i % 3;
    bf16x8 af[2], bfr[4];
#pragma unroll
    for (int m = 0; m < 2; ++m)
      af[m] = *(const bf16x8*)(Als[cb] + (wid * 32 + m * 16 + fr) * 32 + fq * 8);
#pragma unroll
    for (int n = 0; n < 4; ++n)
      bfr[n] = *(const bf16x8*)(Bls[cb] + (n * 16 + fr) * 32 + fq * 8);
    __builtin_amdgcn_s_setprio(1);
#pragma unroll
    for (int m = 0; m < 2; ++m)
#pragma unroll
      for (int n = 0; n < 4; ++n)
        acc[m][n] = __builtin_amdgcn_mfma_f32_16x16x32_bf16(af[m], bfr[n], acc[m][n], 0, 0, 0);
    __builtin_amdgcn_s_setprio(0);

    if (i + 2 < nt) stage((i + 2) % 3, i + 2);
  }

#pragma unroll
  for (int m = 0; m < 2; ++m)
#pragma unroll
    for (int n = 0; n < 4; ++n)
#pragma unroll
      for (int i = 0; i < 4; ++i) {
        int row = bm + wid * 32 + m * 16 + fq * 4 + i;
        int col = bn + n * 16 + fr;
        C[(size_t)row * N + col] = acc[m][n][i];
      }
}

// ---------------- Flash attention, key-split x2, counted-vmcnt pipeline (R13 best) ----------------
// 1024 blocks heavy-first: block = (b,h,qx,chunk); chunk = (qx+1) 64-key tiles.
// 3 buffers, 2-deep prefetch, vmcnt(4); hoisted staging addresses; VALU row-sums.
__global__ __launch_bounds__(256, 4) void attn_fwd(
    const bf16* __restrict__ Q,     // [B*S][DIM] (pre-scaled by log2e/sqrt(D))
    const bf16* __restrict__ KV,    // [B*S][2*DIM] (K = first DIM cols)
    const bf16* __restrict__ Vt,    // [B*NH][HD][S]
    bf16* __restrict__ Opart,       // [1024][128][64] unnormalized partial O
    float* __restrict__ Rpart) {    // [1024][128] partial row sums
  __shared__ __align__(16) bf16 Kls[3][64 * 64];  // [key][a], 128B rows, xor-swizzled
  __shared__ __align__(16) bf16 Vls[3][64 * 64];  // [a][key], 128B rows, xor-swizzled
  const int tid = threadIdx.x, lane = tid & 63, wid = tid >> 6;
  const int l31 = lane & 31, hi = lane >> 5;
  const int bid = blockIdx.x;
  const int qx = 15 - (bid >> 6);   // heavy q-blocks dispatch first
  const int rem = bid & 63;
  const int c = rem >> 5;           // key chunk 0/1
  const int hb = rem & 31;
  const int h = hb >> 1, b = hb & 1;
  const int rw0 = qx * 128 + wid * 32;
  const int qrow = rw0 + l31;
  const float NEGINF = -__builtin_inff();

  const int cnt = qx + 1;           // tiles in this chunk
  const int kt0 = c * cnt;          // first tile
  const int p = ((b * NH + h) * 32) + qx * 2 + c;  // partial index

  bf16x8 qf[4];
#pragma unroll
  for (int ka = 0; ka < 4; ++ka)
    qf[ka] = *(const bf16x8*)(Q + (size_t)(b * S_LEN + qrow) * DIM + h * HD + ka * 16 + hi * 8);

  f32x16 oacc[2] = {};
  float rsA[4] = {0.f, 0.f, 0.f, 0.f};

  // hoisted staging addresses: per-call cost is base + kt*const
  const bf16* kA[2]; const bf16* vA[2]; int obA[2];
#pragma unroll
  for (int j = 0; j < 2; ++j) {
    int ob = (wid * 2 + j) * 1024;
    int o = ob + lane * 16;
    int r = o >> 7;
    int sb = (o & 127) ^ ((r & 7) << 4);
    kA[j] = KV + (size_t)(b * S_LEN + r) * (2 * DIM) + h * HD + (sb >> 1);
    vA[j] = Vt + (size_t)((b * NH + h) * HD + r) * S_LEN + (sb >> 1);
    obA[j] = ob;
  }
  const size_t kStep = (size_t)64 * 2 * DIM;  // K rows advance per tile
  auto stage = [&](int buf, int kt) {
#pragma unroll
    for (int j = 0; j < 2; ++j) {
      gload_lds16(kA[j] + (size_t)kt * kStep, (char*)Kls[buf] + obA[j]);
      gload_lds16(vA[j] + (size_t)kt * 64, (char*)Vls[buf] + obA[j]);
    }
  };

  stage(0, kt0);
  if (cnt > 1) stage(1, kt0 + 1);

  for (int i = 0; i < cnt; ++i) {
    const int kt = kt0 + i;
    if (i + 1 < cnt) asm volatile("s_waitcnt vmcnt(4)" ::: "memory");
    else             asm volatile("s_waitcnt vmcnt(0)" ::: "memory");
    __builtin_amdgcn_s_barrier();
    __builtin_amdgcn_sched_barrier(0);

    const int cb = i % 3;
    if (64 * kt <= rw0 + 31) {
      const bf16* Kb = Kls[cb];
      const bf16* Vb = Vls[cb];
      const bool maskt = (64 * kt + 63 > rw0);

#pragma unroll
      for (int kb = 0; kb < 2; ++kb) {
        f32x16 cc = {};
        __builtin_amdgcn_s_setprio(1);
#pragma unroll
        for (int ka = 0; ka < 4; ++ka) {
          int row = kb * 32 + l31;
          bf16x8 kf = *(const bf16x8*)((const char*)Kb + row * 128 +
                                       ((ka * 32 + hi * 16) ^ ((row & 7) << 4)));
          cc = __builtin_amdgcn_mfma_f32_32x32x16_bf16(kf, qf[ka], cc, 0, 0, 0);
        }
        __builtin_amdgcn_s_setprio(0);

        float pe[16];
        if (maskt) {
#pragma unroll
          for (int r = 0; r < 16; ++r) {
            int key = kt * 64 + kb * 32 + (r & 3) + 8 * (r >> 2) + 4 * hi;
            float s = (key <= qrow) ? cc[r] : NEGINF;
            pe[r] = __builtin_amdgcn_exp2f(s);
            rsA[r & 3] += pe[r];
          }
        } else {
#pragma unroll
          for (int r = 0; r < 16; ++r) {
            pe[r] = __builtin_amdgcn_exp2f(cc[r]);
            rsA[r & 3] += pe[r];
          }
        }

        int u0 = cvt_pk_bf16(pe[0], pe[1]),  u1 = cvt_pk_bf16(pe[2], pe[3]);
        int u2 = cvt_pk_bf16(pe[4], pe[5]),  u3 = cvt_pk_bf16(pe[6], pe[7]);
        int u4 = cvt_pk_bf16(pe[8], pe[9]),  u5 = cvt_pk_bf16(pe[10], pe[11]);
        int u6 = cvt_pk_bf16(pe[12], pe[13]), u7 = cvt_pk_bf16(pe[14], pe[15]);
        asm("v_permlane32_swap_b32 %0, %1" : "+v"(u0), "+v"(u2));
        asm("v_permlane32_swap_b32 %0, %1" : "+v"(u1), "+v"(u3));
        asm("v_permlane32_swap_b32 %0, %1" : "+v"(u4), "+v"(u6));
        asm("v_permlane32_swap_b32 %0, %1" : "+v"(u5), "+v"(u7));
        i32x4 w0, w1;
        w0[0] = u0; w0[1] = u1; w0[2] = u2; w0[3] = u3;
        w1[0] = u4; w1[1] = u5; w1[2] = u6; w1[3] = u7;
        bf16x8 pa0 = as_bf16x8(w0), pa1 = as_bf16x8(w1);

        __builtin_amdgcn_s_setprio(1);
#pragma unroll
        for (int pl = 0; pl < 2; ++pl) {
          bf16x8 pa = pl ? pa1 : pa0;
#pragma unroll
          for (int nb = 0; nb < 2; ++nb) {
            int a = nb * 32 + l31;
            bf16x8 vf = *(const bf16x8*)((const char*)Vb + a * 128 +
                                         ((kb * 64 + pl * 32 + hi * 16) ^ ((a & 7) << 4)));
            oacc[nb] = __builtin_amdgcn_mfma_f32_32x32x16_bf16(pa, vf, oacc[nb], 0, 0, 0);
          }
        }
        __builtin_amdgcn_s_setprio(0);
      }
    }

    if (i + 2 < cnt) stage((i + 2) % 3, kt0 + i + 2);
  }

  float rsum = (rsA[0] + rsA[1]) + (rsA[2] + rsA[3]);
  rsum += __shfl_xor(rsum, 32);
  if (hi == 0) Rpart[p * 128 + wid * 32 + l31] = rsum;
#pragma unroll
  for (int nb = 0; nb < 2; ++nb)
#pragma unroll
    for (int r = 0; r < 16; ++r) {
      int qloc = (r & 3) + 8 * (r >> 2) + 4 * hi;
      Opart[(size_t)p * 8192 + (wid * 32 + qloc) * 64 + nb * 32 + l31] =
          __float2bfloat16(oacc[nb][r]);
    }
}

// ---------------- combine: O = (O0 + O1) / (r0 + r1) ----------------
__global__ __launch_bounds__(256) void attn_combine(
    const bf16* __restrict__ Opart, const float* __restrict__ Rpart,
    bf16* __restrict__ O) {
  const int g = blockIdx.x;          // (b*NH+h)*16 + qx
  const int qx = g & 15, bh = g >> 4;
  const int h = bh & 15, b = bh >> 4;
  const int t = threadIdx.x;
  const int row = t >> 1, col0 = (t & 1) * 32;
  const int p0 = bh * 32 + qx * 2;
  const size_t o0 = (size_t)p0 * 8192 + row * 64 + col0;
  const float rinv = 1.0f / (Rpart[p0 * 128 + row] + Rpart[p0 * 128 + 128 + row]);
  const int s = qx * 128 + row;
  bf16* dst = O + (size_t)(b * S_LEN + s) * DIM + h * HD + col0;
#pragma unroll
  for (int j = 0; j < 4; ++j) {
    bf16x8 a = *(const bf16x8*)(Opart + o0 + j * 8);
    bf16x8 cc = *(const bf16x8*)(Opart + o0 + 8192 + j * 8);
    bf16x8 w;
#pragma unroll
    for (int e = 0; e < 8; ++e) {
      bf16 r = __float2bfloat16((b2f(a[e]) + b2f(cc[e])) * rinv);
      ((short*)&w)[e] = *(short*)&r;
    }
    *(bf16x8*)(dst + j * 8) = w;
  }
}

// ---------------- launch ----------------
extern "C" void kernel_launch(void* const* d_in, const int* in_sizes, int n_in,
                              void* d_out, int out_size, void* d_ws, size_t ws_size,
                              hipStream_t stream) {
  (void)in_sizes; (void)n_in; (void)out_size; (void)ws_size;
  const float* query   = (const float*)d_in[0];
  const float* context = (const float*)d_in[1];
  const float* Wq      = (const float*)d_in[2];
  const float* Wkv     = (const float*)d_in[3];
  const float* Wout    = (const float*)d_in[4];
  float* out = (float*)d_out;

  bf16* ws = (bf16*)d_ws;
  const size_t nBSD = (size_t)BATCH * S_LEN * DIM;  // 4194304
  bf16* qbf    = ws;
  bf16* cbf    = qbf + nBSD;
  bf16* wqbf   = cbf + nBSD;
  bf16* wkvbf  = wqbf + (size_t)DIM * DIM;
  bf16* woutbf = wkvbf + (size_t)2 * DIM * DIM;
  bf16* Qp     = woutbf + (size_t)DIM * DIM;
  bf16* KVp    = Qp + nBSD;
  bf16* Vtp    = KVp + 2 * nBSD;
  bf16* Op     = Vtp + nBSD;
  // after gemm_proj, qbf/cbf/wqbf are dead -> reuse for attention partials
  bf16*  Opart = qbf;            // 1024*128*64 bf16 = 16.8 MB
  float* Rpart = (float*)wqbf;   // 1024*128 fp32 = 512 KB

  // fused conversions
  cvt_all<<<2048, 256, 0, stream>>>(query, context, Wq, Wkv, Wout,
                                    qbf, cbf, wqbf, wkvbf, woutbf);

  // Q-proj (scaled by log2e/sqrt(D)) + KV-proj grouped; V-half written transposed to Vtp
  gemm_proj<<<768, 256, 0, stream>>>(qbf, wqbf, Qp, cbf, wkvbf, KVp, Vtp,
                                     0.0450842200277801f);

  // attention: 1024 key-split blocks, heavy-first
  attn_fwd<<<1024, 256, 0, stream>>>(Qp, KVp, Vtp, Opart, Rpart);
  // combine partials -> Op
  attn_combine<<<512, 256, 0, stream>>>(Opart, Rpart, Op);
  // out = O * Wout^T  (BN=64 -> 512 blocks, pipelined, 1D grid)
  const int M = BATCH * S_LEN;
  gemm_bt_n64<<<512, 256, 0, stream>>>(Op, woutbf, out, M, DIM, DIM);
}